// Round 1
// baseline (109.407 us; speedup 1.0000x reference)
//
#include <hip/hip_runtime.h>
#include <math.h>

#define N_PTS 16384
#define M_TGT 16384
#define TPN 8192
#define DUB2 4.0f
#define KEYSPACE (4*64*64*64)
#define BMASK_WORDS (KEYSPACE/32)
#define NSLICE 8
#define TS (M_TGT / NSLICE)

__device__ __forceinline__ unsigned int mono_key(float f) {
    unsigned int u = __float_as_uint(f);
    return (u & 0x80000000u) ? ~u : (u | 0x80000000u);
}

// K1: fea_up = relu(fea @ Wup); pred = fea_up @ Wcls
// 16 rows per block, 256 threads: thread = (row r = tid>>4, colgroup cg = tid&15 -> 4 cols)
__global__ __launch_bounds__(256) void k_gemm(const float* __restrict__ fea,
        const float* __restrict__ Wup, const float* __restrict__ Wcls,
        float* __restrict__ out_pred, float* __restrict__ out_fea) {
    __shared__ float Ws[64 * 64];
    __shared__ float fs[16 * 68];   // +4 pad breaks bank aliasing on fs[r][k]
    const int tid = threadIdx.x;
    const int r0 = blockIdx.x * 16;

    for (int t = tid; t < 1024; t += 256)
        ((float4*)Ws)[t] = ((const float4*)Wup)[t];
    {
        float4 v = ((const float4*)(fea + r0 * 64))[tid];
        int r = tid >> 4, c = (tid & 15) * 4;
        fs[r*68 + c + 0] = v.x; fs[r*68 + c + 1] = v.y;
        fs[r*68 + c + 2] = v.z; fs[r*68 + c + 3] = v.w;
    }
    __syncthreads();

    const int cg = tid & 15;
    const int r  = tid >> 4;
    float a0 = 0.f, a1 = 0.f, a2 = 0.f, a3 = 0.f;
    const float* fr = fs + r * 68;
    #pragma unroll
    for (int k = 0; k < 64; ++k) {
        float f = fr[k];
        float4 w = *(const float4*)&Ws[k * 64 + cg * 4];
        a0 = fmaf(f, w.x, a0); a1 = fmaf(f, w.y, a1);
        a2 = fmaf(f, w.z, a2); a3 = fmaf(f, w.w, a3);
    }
    a0 = fmaxf(a0, 0.f); a1 = fmaxf(a1, 0.f);
    a2 = fmaxf(a2, 0.f); a3 = fmaxf(a3, 0.f);
    const int row = r0 + r;
    *(float4*)&out_fea[row * 64 + cg * 4] = make_float4(a0, a1, a2, a3);

    float4 wc = *(const float4*)&Wcls[cg * 4];
    float s = a0*wc.x + a1*wc.y + a2*wc.z + a3*wc.w;
    for (int off = 1; off < 16; off <<= 1) s += __shfl_xor(s, off, 16);
    if (cg == 0) out_pred[row] = s;
}

// K2: radix-select 8192nd smallest of p (exact order statistic), single block
__global__ __launch_bounds__(1024) void k_select(const float* __restrict__ p,
                                                 float* __restrict__ thres_out) {
    __shared__ unsigned int hist[256];
    __shared__ unsigned int sh_prefix, sh_rank;
    const int tid = threadIdx.x;
    if (tid == 0) { sh_prefix = 0u; sh_rank = TPN - 1; }
    for (int pass = 0; pass < 4; ++pass) {
        const int shift = 24 - pass * 8;
        if (tid < 256) hist[tid] = 0u;
        __syncthreads();
        const unsigned int prefix = sh_prefix;
        for (int i = tid; i < N_PTS; i += 1024) {
            unsigned int u = mono_key(p[i]);
            bool match = (pass == 0) || ((u >> (shift + 8)) == prefix);
            if (match) atomicAdd(&hist[(u >> shift) & 255u], 1u);
        }
        __syncthreads();
        if (tid == 0) {
            unsigned int r = sh_rank, cum = 0u, b = 0u;
            for (; b < 256u; ++b) {
                unsigned int c = hist[b];
                if (r < cum + c) { r -= cum; break; }
                cum += c;
            }
            sh_prefix = (prefix << 8) | b;
            sh_rank = r;
        }
        __syncthreads();
    }
    if (tid == 0) {
        unsigned int u = sh_prefix;
        thres_out[0] = (u & 0x80000000u) ? __uint_as_float(u ^ 0x80000000u)
                                         : __uint_as_float(~u);
    }
}

// K3: build key bitmask + precompute target (-2x,-2y,-2z,-2w) and |t|^2, w=128*batch
__global__ __launch_bounds__(256) void k_prep(const int* __restrict__ tc,
        unsigned int* __restrict__ bmask, float4* __restrict__ m2t,
        float* __restrict__ tt) {
    const int j = blockIdx.x * 256 + threadIdx.x;
    if (j >= M_TGT) return;
    int4 c = *(const int4*)&tc[j * 4];                 // (b,x,y,z)
    int key = ((c.x * 64 + c.y) * 64 + c.z) * 64 + c.w;
    atomicOr(&bmask[key >> 5], 1u << (key & 31));
    float x = (float)c.y, y = (float)c.z, z = (float)c.w, w = 128.0f * (float)c.x;
    m2t[j] = make_float4(-2.f * x, -2.f * y, -2.f * z, -2.f * w);
    tt[j] = x * x + y * y + z * z + w * w;
}

// K4: brute-force NN: block = (point-chunk pb, target-slice s); partial min per slice
__global__ __launch_bounds__(256) void k_nn(const int* __restrict__ coords,
        const float4* __restrict__ m2t, const float* __restrict__ tt,
        float* __restrict__ partial) {
    __shared__ float4 m2s[TS];
    __shared__ float tts[TS];
    const int tid = threadIdx.x;
    const int s  = blockIdx.x & (NSLICE - 1);
    const int pb = blockIdx.x >> 3;
    const int j0 = s * TS;
    for (int k = tid; k < TS; k += 256) { m2s[k] = m2t[j0 + k]; tts[k] = tt[j0 + k]; }
    __syncthreads();

    const int i = pb * 256 + tid;
    int4 c = *(const int4*)&coords[i * 4];
    const float px = (float)c.y, py = (float)c.z, pz = (float)c.w;
    const float pw = 128.0f * (float)c.x;
    const float pp = px*px + py*py + pz*pz + pw*pw;

    float m0 = 3.4e38f, m1 = 3.4e38f, m2v = 3.4e38f, m3 = 3.4e38f;
    for (int j = 0; j < TS; j += 4) {
        {
            float d = pp + tts[j + 0]; float4 mm = m2s[j + 0];
            d = fmaf(mm.x, px, d); d = fmaf(mm.y, py, d);
            d = fmaf(mm.z, pz, d); d = fmaf(mm.w, pw, d);
            m0 = fminf(m0, d);
        }
        {
            float d = pp + tts[j + 1]; float4 mm = m2s[j + 1];
            d = fmaf(mm.x, px, d); d = fmaf(mm.y, py, d);
            d = fmaf(mm.z, pz, d); d = fmaf(mm.w, pw, d);
            m1 = fminf(m1, d);
        }
        {
            float d = pp + tts[j + 2]; float4 mm = m2s[j + 2];
            d = fmaf(mm.x, px, d); d = fmaf(mm.y, py, d);
            d = fmaf(mm.z, pz, d); d = fmaf(mm.w, pw, d);
            m2v = fminf(m2v, d);
        }
        {
            float d = pp + tts[j + 3]; float4 mm = m2s[j + 3];
            d = fmaf(mm.x, px, d); d = fmaf(mm.y, py, d);
            d = fmaf(mm.z, pz, d); d = fmaf(mm.w, pw, d);
            m3 = fminf(m3, d);
        }
    }
    partial[i * NSLICE + s] = fminf(fminf(m0, m1), fminf(m2v, m3));
}

// K5: epilogue — keep/keep_target/loss + scale fea_pruned in place. 64 rows/block.
__global__ __launch_bounds__(256) void k_final(const int* __restrict__ coords,
        const unsigned int* __restrict__ bmask, const float* __restrict__ thres_p,
        const float* __restrict__ partial,
        const float* __restrict__ out_pred, float* __restrict__ out_fea,
        float* __restrict__ out_keep, float* __restrict__ out_kt,
        float* __restrict__ out_loss) {
    __shared__ float kscale[64];
    const int tid = threadIdx.x;
    const int r0 = blockIdx.x * 64;
    if (tid < 64) {
        const int i = r0 + tid;
        float p = out_pred[i];
        float thres = thres_p[0];
        float dmin = 3.4e38f;
        #pragma unroll
        for (int s = 0; s < NSLICE; ++s) dmin = fminf(dmin, partial[i * NSLICE + s]);
        float dists = fmaxf(dmin, 0.f);
        int4 c = *(const int4*)&coords[i * 4];
        int key = ((c.x * 64 + c.y) * 64 + c.z) * 64 + c.w;
        bool kt = (bmask[key >> 5] >> (key & 31)) & 1u;
        bool keep0 = (p <= thres);
        bool pm = (p > DUB2), tm = (dists > DUB2);
        float loss = (pm && tm) ? p : ((!pm && tm) ? DUB2 : dists);
        bool kf = keep0 || kt;
        out_keep[i] = kf ? 1.f : 0.f;
        out_kt[i]  = kt ? 1.f : 0.f;
        out_loss[i] = loss;
        kscale[tid] = kf ? 1.f : 0.f;
    }
    __syncthreads();
    float4* fbase = (float4*)(out_fea + r0 * 64);
    #pragma unroll
    for (int q = 0; q < 4; ++q) {
        int v = tid + q * 256;
        float sc = kscale[v >> 4];
        float4 x = fbase[v];
        x.x *= sc; x.y *= sc; x.z *= sc; x.w *= sc;
        fbase[v] = x;
    }
}

extern "C" void kernel_launch(void* const* d_in, const int* in_sizes, int n_in,
                              void* d_out, int out_size, void* d_ws, size_t ws_size,
                              hipStream_t stream) {
    const float* fea     = (const float*)d_in[0];
    const float* Wup     = (const float*)d_in[1];
    const float* Wcls    = (const float*)d_in[2];
    const int*   coords  = (const int*)d_in[3];
    const int*   tcoords = (const int*)d_in[4];

    float* out      = (float*)d_out;
    float* out_pred = out;
    float* out_fea  = out + N_PTS;
    float* out_keep = out + N_PTS + N_PTS * 64;
    float* out_kt   = out_keep + N_PTS;
    float* out_loss = out_kt + N_PTS;

    char* ws = (char*)d_ws;
    float*        thres   = (float*)ws;                       // 4 B (padded 256)
    unsigned int* bmask   = (unsigned int*)(ws + 256);        // 128 KB
    float4*       m2t     = (float4*)(ws + 256 + 131072);     // 256 KB
    float*        tt      = (float*)(ws + 256 + 131072 + 262144);          // 64 KB
    float*        partial = (float*)(ws + 256 + 131072 + 262144 + 65536);  // 512 KB

    k_gemm  <<<N_PTS / 16, 256, 0, stream>>>(fea, Wup, Wcls, out_pred, out_fea);
    k_select<<<1, 1024, 0, stream>>>(out_pred, thres);
    hipMemsetAsync(bmask, 0, BMASK_WORDS * sizeof(unsigned int), stream);
    k_prep  <<<M_TGT / 256, 256, 0, stream>>>(tcoords, bmask, m2t, tt);
    k_nn    <<<(N_PTS / 256) * NSLICE, 256, 0, stream>>>(coords, m2t, tt, partial);
    k_final <<<N_PTS / 64, 256, 0, stream>>>(coords, bmask, thres, partial,
                                             out_pred, out_fea, out_keep, out_kt, out_loss);
}